// Round 1
// baseline (843.337 us; speedup 1.0000x reference)
//
#include <hip/hip_runtime.h>

#define SEQ   1024
#define BATCH 1024
#define TAG   32
#define NEGV  (-10000.0f)
#define START 30      // TAG-2
#define ENDT  31      // TAG-1
#define PF    8       // prefetch depth (steps)

__global__ __launch_bounds__(64) void crf_fwd_kernel(
    const float* __restrict__ feats,   // (SEQ, BATCH, TAG)
    const float* __restrict__ mask,    // (SEQ, BATCH)
    const float* __restrict__ trans,   // (TAG, TAG)
    float* __restrict__ out)           // (BATCH,)
{
    const int lane = threadIdx.x;      // 0..63 (single wave per block)
    const int g    = lane >> 5;        // batch group within wave: 0/1
    const int i    = lane & 31;        // tag index
    const int b    = blockIdx.x * 2 + g;

    __shared__ float u_lds[2][32];

    // --- Precompute E[i][j] = exp(trans[i][j]) for this lane's row i ---
    float e[32];
    {
        const float4* tr4 = reinterpret_cast<const float4*>(trans + i * TAG);
        #pragma unroll
        for (int c = 0; c < 8; ++c) {
            float4 v = tr4[c];
            e[4 * c + 0] = __expf(v.x);
            e[4 * c + 1] = __expf(v.y);
            e[4 * c + 2] = __expf(v.z);
            e[4 * c + 3] = __expf(v.w);
        }
    }

    // --- Initial state: alpha[START]=0, else NEG; m = max = 0 ---
    float alpha = (i == START) ? 0.0f : NEGV;
    float m = 0.0f;

    // --- Prefetch ring for feats and mask ---
    const float* fp = feats + (size_t)b * TAG + i;  // advance by BATCH*TAG per t
    float fbuf[PF], mbuf[PF];
    #pragma unroll
    for (int p = 0; p < PF; ++p) {
        fbuf[p] = fp[(size_t)p * (BATCH * TAG)];
        mbuf[p] = mask[(size_t)p * BATCH + b];
    }

    const float4* u4 = reinterpret_cast<const float4*>(u_lds[g]);

    for (int t0 = 0; t0 < SEQ; t0 += PF) {
        #pragma unroll
        for (int p = 0; p < PF; ++p) {
            const int t = t0 + p;

            // u[i] = exp(alpha[i] - m), share within the 32-lane batch group
            float u = __expf(alpha - m);
            u_lds[g][i] = u;
            __syncthreads();   // single-wave block: cheap lgkmcnt drain

            // dot: s = sum_j u[j] * E[i][j]   (broadcast reads from LDS)
            float s0 = 0.0f, s1 = 0.0f, s2 = 0.0f, s3 = 0.0f;
            #pragma unroll
            for (int c = 0; c < 8; ++c) {
                float4 uv = u4[c];
                s0 = fmaf(uv.x, e[4 * c + 0], s0);
                s1 = fmaf(uv.y, e[4 * c + 1], s1);
                s2 = fmaf(uv.z, e[4 * c + 2], s2);
                s3 = fmaf(uv.w, e[4 * c + 3], s3);
            }
            float s = (s0 + s1) + (s2 + s3);

            float anew = fbuf[p] + m + __logf(s);
            // mask blend as a select (avoids -inf*0 NaN)
            alpha = (mbuf[p] != 0.0f) ? anew : alpha;

            // prefetch step t+PF (clamped; redundant loads at tail are harmless)
            int tn = t + PF; tn = (tn < SEQ) ? tn : (SEQ - 1);
            fbuf[p] = fp[(size_t)tn * (BATCH * TAG)];
            mbuf[p] = mask[(size_t)tn * BATCH + b];

            // recompute running max m = max_j alpha[j] within the 32-lane group
            float mm = alpha;
            #pragma unroll
            for (int k = 16; k >= 1; k >>= 1)
                mm = fmaxf(mm, __shfl_xor(mm, k, 32));
            m = mm;
        }
    }

    // --- Epilogue: out[b] = logsumexp_i(alpha[i] + trans[END][i]) ---
    float v = alpha + trans[ENDT * TAG + i];
    float mx = v;
    #pragma unroll
    for (int k = 16; k >= 1; k >>= 1)
        mx = fmaxf(mx, __shfl_xor(mx, k, 32));
    float ee = __expf(v - mx);
    float ss = ee;
    #pragma unroll
    for (int k = 16; k >= 1; k >>= 1)
        ss += __shfl_xor(ss, k, 32);
    if (i == 0) out[b] = mx + __logf(ss);
}

extern "C" void kernel_launch(void* const* d_in, const int* in_sizes, int n_in,
                              void* d_out, int out_size, void* d_ws, size_t ws_size,
                              hipStream_t stream) {
    const float* feats = (const float*)d_in[0];
    const float* mask  = (const float*)d_in[1];
    const float* trans = (const float*)d_in[2];
    float* out = (float*)d_out;
    crf_fwd_kernel<<<dim3(BATCH / 2), dim3(64), 0, stream>>>(feats, mask, trans, out);
}

// Round 2
// 506.856 us; speedup vs baseline: 1.6639x; 1.6639x over previous
//
#include <hip/hip_runtime.h>

#define SEQ   1024
#define BATCH 1024
#define TAG   32
#define START 30      // TAG-2
#define ENDT  31      // TAG-1
#define PFD   8       // prefetch ring depth (steps)
#define NCH   2       // interleaved batch-pair chains per wave
#define BT    (BATCH*TAG)

#define MAX3(a,b,c) fmaxf(fmaxf((a),(b)),(c))

__device__ __forceinline__ float dot32(const float4* __restrict__ v,
                                       const float* __restrict__ e) {
    float s0 = 0.f, s1 = 0.f, s2 = 0.f, s3 = 0.f;
    #pragma unroll
    for (int c = 0; c < 8; ++c) {
        s0 = fmaf(v[c].x, e[4 * c + 0], s0);
        s1 = fmaf(v[c].y, e[4 * c + 1], s1);
        s2 = fmaf(v[c].z, e[4 * c + 2], s2);
        s3 = fmaf(v[c].w, e[4 * c + 3], s3);
    }
    return (s0 + s1) + (s2 + s3);
}

__device__ __forceinline__ float max32(const float4* __restrict__ v) {
    // 3-ary tree -> v_max3_f32 fusion, depth 3
    float n0 = MAX3(v[0].x, v[0].y, v[0].z);
    float n1 = MAX3(v[0].w, v[1].x, v[1].y);
    float n2 = MAX3(v[1].z, v[1].w, v[2].x);
    float n3 = MAX3(v[2].y, v[2].z, v[2].w);
    float n4 = MAX3(v[3].x, v[3].y, v[3].z);
    float n5 = MAX3(v[3].w, v[4].x, v[4].y);
    float n6 = MAX3(v[4].z, v[4].w, v[5].x);
    float n7 = MAX3(v[5].y, v[5].z, v[5].w);
    float n8 = MAX3(v[6].x, v[6].y, v[6].z);
    float n9 = MAX3(v[6].w, v[7].x, v[7].y);
    float p0 = MAX3(n0, n1, n2);
    float p1 = MAX3(n3, n4, n5);
    float p2 = MAX3(n6, n7, n8);
    float p3 = MAX3(n9, v[7].z, v[7].w);
    return fmaxf(fmaxf(p0, p1), fmaxf(p2, p3));
}

// One CRF step in u-space.  Invariant: alpha_j = mA + ln(u_j).
// u'_i = (sum_j E[i][j] u_j) * exp(feat_i) * (NORM ? 1/max_u : 1)
// mA'  = mA + (NORM ? ln(max_u) : 0)          [off the critical chain]
template <bool NORM>
__device__ __forceinline__ void crf_step(const float4* __restrict__ v,
                                         const float* __restrict__ e,
                                         float fv, float mv,
                                         float& u, float& mA) {
    float s  = dot32(v, e);
    float ef = __expf(fv);
    float un, mAn = mA;
    if (NORM) {
        float mx = max32(v);
        float r  = __builtin_amdgcn_rcpf(mx);
        un  = s * r * ef;
        mAn = mA + __logf(mx);
    } else {
        un = s * ef;
    }
    bool act = (mv != 0.0f);
    u  = act ? un : u;
    mA = act ? mAn : mA;
}

__global__ __launch_bounds__(64) void crf_fwd_kernel(
    const float* __restrict__ feats,   // (SEQ, BATCH, TAG)
    const float* __restrict__ mask,    // (SEQ, BATCH)
    const float* __restrict__ trans,   // (TAG, TAG)
    float* __restrict__ out)           // (BATCH,)
{
    const int lane = threadIdx.x;
    const int g    = lane >> 5;        // batch group within wave
    const int i    = lane & 31;        // tag index

    __shared__ __align__(16) float uL[NCH][2][32];

    // E[i][j] = exp(trans[i][j]); NEG rows/cols underflow to exactly 0.
    float e[32];
    {
        const float4* tr4 = reinterpret_cast<const float4*>(trans + i * TAG);
        #pragma unroll
        for (int c = 0; c < 8; ++c) {
            float4 v = tr4[c];
            e[4 * c + 0] = __expf(v.x);
            e[4 * c + 1] = __expf(v.y);
            e[4 * c + 2] = __expf(v.z);
            e[4 * c + 3] = __expf(v.w);
        }
    }
    const float tEnd = trans[ENDT * TAG + i];

    int b[NCH];
    const float* fp[NCH];
    const float* mp[NCH];
    float u[NCH], mAcc[NCH];
    #pragma unroll
    for (int c = 0; c < NCH; ++c) {
        b[c]    = blockIdx.x * (2 * NCH) + c * 2 + g;
        fp[c]   = feats + (size_t)b[c] * TAG + i;
        mp[c]   = mask + b[c];
        u[c]    = (i == START) ? 1.0f : 0.0f;   // exp(alpha0 - 0)
        mAcc[c] = 0.0f;
        uL[c][g][i] = u[c];
    }

    // prefetch rings
    float fb[NCH][PFD], mb[NCH][PFD];
    #pragma unroll
    for (int p = 0; p < PFD; ++p) {
        #pragma unroll
        for (int c = 0; c < NCH; ++c) {
            fb[c][p] = fp[c][(size_t)p * BT];
            mb[c][p] = mp[c][(size_t)p * BATCH];
        }
    }

    for (int t0 = 0; t0 < SEQ; t0 += PFD) {
        // masks are monotone non-increasing in t; if all 4 batches done, stop
        if (__ballot(mb[0][0] + mb[1][0] != 0.0f) == 0ull) break;

        #pragma unroll
        for (int p = 0; p < PFD; ++p) {
            const int t = t0 + p;

            // issue both chains' u-vector reads (broadcast b128, conflict-free)
            float4 v0[8], v1[8];
            {
                const float4* q0 = reinterpret_cast<const float4*>(uL[0][g]);
                const float4* q1 = reinterpret_cast<const float4*>(uL[1][g]);
                #pragma unroll
                for (int c = 0; c < 8; ++c) v0[c] = q0[c];
                #pragma unroll
                for (int c = 0; c < 8; ++c) v1[c] = q1[c];
            }

            // chain 0 compute + state write; chain 1's reads hide underneath
            if ((p & 3) == 0) crf_step<true >(v0, e, fb[0][p], mb[0][p], u[0], mAcc[0]);
            else              crf_step<false>(v0, e, fb[0][p], mb[0][p], u[0], mAcc[0]);
            uL[0][g][i] = u[0];

            if ((p & 3) == 0) crf_step<true >(v1, e, fb[1][p], mb[1][p], u[1], mAcc[1]);
            else              crf_step<false>(v1, e, fb[1][p], mb[1][p], u[1], mAcc[1]);
            uL[1][g][i] = u[1];

            // refill ring for step t+PFD (clamped; tail re-reads are harmless)
            int tn = t + PFD; tn = (tn < SEQ) ? tn : (SEQ - 1);
            #pragma unroll
            for (int c = 0; c < NCH; ++c) {
                fb[c][p] = fp[c][(size_t)tn * BT];
                mb[c][p] = mp[c][(size_t)tn * BATCH];
            }
        }
    }

    // Epilogue: out[b] = mA + ln( sum_i u_i * exp(trans[END][i]) )
    const float eEnd = __expf(tEnd);
    #pragma unroll
    for (int c = 0; c < NCH; ++c) {
        float vsum = u[c] * eEnd;
        #pragma unroll
        for (int k = 16; k >= 1; k >>= 1)
            vsum += __shfl_xor(vsum, k, 32);
        if (i == 0) out[b[c]] = mAcc[c] + __logf(vsum);
    }
}

extern "C" void kernel_launch(void* const* d_in, const int* in_sizes, int n_in,
                              void* d_out, int out_size, void* d_ws, size_t ws_size,
                              hipStream_t stream) {
    const float* feats = (const float*)d_in[0];
    const float* mask  = (const float*)d_in[1];
    const float* trans = (const float*)d_in[2];
    float* out = (float*)d_out;
    crf_fwd_kernel<<<dim3(BATCH / (2 * NCH)), dim3(64), 0, stream>>>(feats, mask, trans, out);
}

// Round 3
// 487.471 us; speedup vs baseline: 1.7300x; 1.0398x over previous
//
#include <hip/hip_runtime.h>

#define SEQ   1024
#define BATCH 1024
#define TAG   32
#define START 30      // TAG-2
#define ENDT  31      // TAG-1
#define PFD   8       // prefetch ring depth (steps)
#define NCH   2       // interleaved batch-pair chains per wave
#define BT    (BATCH*TAG)

#define MAX3(a,b,c) fmaxf(fmaxf((a),(b)),(c))

// 8 accumulators -> dependency depth 4 fmas (16 cy) + 12 cy add tree
__device__ __forceinline__ float dot32(const float4* __restrict__ v,
                                       const float* __restrict__ e) {
    float s0=0.f,s1=0.f,s2=0.f,s3=0.f,s4=0.f,s5=0.f,s6=0.f,s7=0.f;
    #pragma unroll
    for (int c = 0; c < 4; ++c) {
        s0 = fmaf(v[2*c  ].x, e[8*c+0], s0);
        s1 = fmaf(v[2*c  ].y, e[8*c+1], s1);
        s2 = fmaf(v[2*c  ].z, e[8*c+2], s2);
        s3 = fmaf(v[2*c  ].w, e[8*c+3], s3);
        s4 = fmaf(v[2*c+1].x, e[8*c+4], s4);
        s5 = fmaf(v[2*c+1].y, e[8*c+5], s5);
        s6 = fmaf(v[2*c+1].z, e[8*c+6], s6);
        s7 = fmaf(v[2*c+1].w, e[8*c+7], s7);
    }
    return ((s0+s1)+(s2+s3)) + ((s4+s5)+(s6+s7));
}

__device__ __forceinline__ float max32(const float4* __restrict__ v) {
    float n0 = MAX3(v[0].x, v[0].y, v[0].z);
    float n1 = MAX3(v[0].w, v[1].x, v[1].y);
    float n2 = MAX3(v[1].z, v[1].w, v[2].x);
    float n3 = MAX3(v[2].y, v[2].z, v[2].w);
    float n4 = MAX3(v[3].x, v[3].y, v[3].z);
    float n5 = MAX3(v[3].w, v[4].x, v[4].y);
    float n6 = MAX3(v[4].z, v[4].w, v[5].x);
    float n7 = MAX3(v[5].y, v[5].z, v[5].w);
    float n8 = MAX3(v[6].x, v[6].y, v[6].z);
    float n9 = MAX3(v[6].w, v[7].x, v[7].y);
    float p0 = MAX3(n0, n1, n2);
    float p1 = MAX3(n3, n4, n5);
    float p2 = MAX3(n6, n7, n8);
    float p3 = MAX3(n9, v[7].z, v[7].w);
    return fmaxf(fmaxf(p0, p1), fmaxf(p2, p3));
}

// One CRF step in u-space.  Invariant: alpha_j = mA + ln(u_j).
template <bool NORM>
__device__ __forceinline__ void crf_step(const float4* __restrict__ v,
                                         const float* __restrict__ e,
                                         float fv, float mv,
                                         float& u, float& mA) {
    float s  = dot32(v, e);
    float ef = __expf(fv);       // off-chain (fv from prefetch ring)
    float un, mAn = mA;
    if (NORM) {
        float mx = max32(v);
        float r  = __builtin_amdgcn_rcpf(mx);
        un  = s * r * ef;
        mAn = mA + __logf(mx);
    } else {
        un = s * ef;
    }
    bool act = (mv != 0.0f);
    u  = act ? un : u;
    mA = act ? mAn : mA;
}

__global__ __launch_bounds__(64) void crf_fwd_kernel(
    const float* __restrict__ feats,   // (SEQ, BATCH, TAG)
    const float* __restrict__ mask,    // (SEQ, BATCH)
    const float* __restrict__ trans,   // (TAG, TAG)
    float* __restrict__ out)           // (BATCH,)
{
    const int lane = threadIdx.x;
    const int g    = lane >> 5;        // batch group within wave
    const int i    = lane & 31;        // tag index

    __shared__ __align__(16) float uL[NCH][2][32];

    // E[i][j] = exp(trans[i][j]); NEG rows/cols underflow to exactly 0.
    float e[32];
    {
        const float4* tr4 = reinterpret_cast<const float4*>(trans + i * TAG);
        #pragma unroll
        for (int c = 0; c < 8; ++c) {
            float4 v = tr4[c];
            e[4 * c + 0] = __expf(v.x);
            e[4 * c + 1] = __expf(v.y);
            e[4 * c + 2] = __expf(v.z);
            e[4 * c + 3] = __expf(v.w);
        }
    }
    const float tEnd = trans[ENDT * TAG + i];

    int b[NCH];
    const float* fp[NCH];
    const float* mp[NCH];
    float u[NCH], mAcc[NCH];
    #pragma unroll
    for (int c = 0; c < NCH; ++c) {
        b[c]    = blockIdx.x * (2 * NCH) + c * 2 + g;
        fp[c]   = feats + (size_t)b[c] * TAG + i;
        mp[c]   = mask + b[c];
        u[c]    = (i == START) ? 1.0f : 0.0f;   // exp(alpha0 - 0)
        mAcc[c] = 0.0f;
        uL[c][g][i] = u[c];
    }

    // prefetch rings for feats / mask
    float fb[NCH][PFD], mb[NCH][PFD];
    #pragma unroll
    for (int p = 0; p < PFD; ++p) {
        #pragma unroll
        for (int c = 0; c < NCH; ++c) {
            fb[c][p] = fp[c][(size_t)p * BT];
            mb[c][p] = mp[c][(size_t)p * BATCH];
        }
    }

    // Pre-read both chains' u-vectors (skewed pipeline priming)
    const float4* q0 = reinterpret_cast<const float4*>(uL[0][g]);
    const float4* q1 = reinterpret_cast<const float4*>(uL[1][g]);
    float4 V0[8], V1[8];
    #pragma unroll
    for (int c = 0; c < 8; ++c) V0[c] = q0[c];
    #pragma unroll
    for (int c = 0; c < 8; ++c) V1[c] = q1[c];

    for (int t0 = 0; t0 < SEQ; t0 += PFD) {
        // masks are monotone non-increasing in t; if all batches done, stop
        if (__ballot(mb[0][0] + mb[1][0] != 0.0f) == 0ull) break;

        #pragma unroll
        for (int p = 0; p < PFD; ++p) {
            const int t = t0 + p;

            // ---- chain 0: compute from pre-read V0, write, re-read ----
            if ((p & 3) == 0) crf_step<true >(V0, e, fb[0][p], mb[0][p], u[0], mAcc[0]);
            else              crf_step<false>(V0, e, fb[0][p], mb[0][p], u[0], mAcc[0]);
            uL[0][g][i] = u[0];
            #pragma unroll
            for (int c = 0; c < 8; ++c) V0[c] = q0[c];   // round-trip hides under chain 1

            // ---- chain 1 ----
            if ((p & 3) == 0) crf_step<true >(V1, e, fb[1][p], mb[1][p], u[1], mAcc[1]);
            else              crf_step<false>(V1, e, fb[1][p], mb[1][p], u[1], mAcc[1]);
            uL[1][g][i] = u[1];
            #pragma unroll
            for (int c = 0; c < 8; ++c) V1[c] = q1[c];   // hides under next step's chain 0

            // refill ring for step t+PFD (clamped; tail re-reads are harmless)
            int tn = t + PFD; tn = (tn < SEQ) ? tn : (SEQ - 1);
            #pragma unroll
            for (int c = 0; c < NCH; ++c) {
                fb[c][p] = fp[c][(size_t)tn * BT];
                mb[c][p] = mp[c][(size_t)tn * BATCH];
            }
        }
    }

    // Epilogue: out[b] = mA + ln( sum_i u_i * exp(trans[END][i]) )
    const float eEnd = __expf(tEnd);
    #pragma unroll
    for (int c = 0; c < NCH; ++c) {
        float vsum = u[c] * eEnd;
        #pragma unroll
        for (int k = 16; k >= 1; k >>= 1)
            vsum += __shfl_xor(vsum, k, 32);
        if (i == 0) out[b[c]] = mAcc[c] + __logf(vsum);
    }
}

extern "C" void kernel_launch(void* const* d_in, const int* in_sizes, int n_in,
                              void* d_out, int out_size, void* d_ws, size_t ws_size,
                              hipStream_t stream) {
    const float* feats = (const float*)d_in[0];
    const float* mask  = (const float*)d_in[1];
    const float* trans = (const float*)d_in[2];
    float* out = (float*)d_out;
    crf_fwd_kernel<<<dim3(BATCH / (2 * NCH)), dim3(64), 0, stream>>>(feats, mask, trans, out);
}

// Round 4
// 362.480 us; speedup vs baseline: 2.3266x; 1.3448x over previous
//
#include <hip/hip_runtime.h>

#define SEQ   1024
#define BATCH 1024
#define TAG   32
#define START 30      // TAG-2
#define ENDT  31      // TAG-1
#define PFD   8       // prefetch ring depth (steps)
#define BT    (BATCH*TAG)   // 32768 = 2^15  -> shift addressing

__device__ __forceinline__ float rdlane(float v, int j) {
    return __uint_as_float(__builtin_amdgcn_readlane(__float_as_uint(v), j));
}

// One wave = one batch. Lanes 0..31 and 32..63 hold identical state (tag i = lane&31).
// Invariant: alpha_i = mA + ln(v_i), with v renormalized by v[0] every step
// (v[0] > 0 strictly after step 1; v_i/v_0 bounded within ~e^18 each step).
__global__ __launch_bounds__(64) void crf_fwd_kernel(
    const float* __restrict__ feats,   // (SEQ, BATCH, TAG)
    const float* __restrict__ mask,    // (SEQ, BATCH)
    const float* __restrict__ trans,   // (TAG, TAG)
    float* __restrict__ out)           // (BATCH,)
{
    const int lane = threadIdx.x;
    const int i    = lane & 31;        // tag index (duplicated across halves)
    const int b    = blockIdx.x;       // one batch per block/wave

    // E[i][j] = exp(trans[i][j]); NEG row START / col END underflow to exactly 0.
    float e[32];
    {
        const float4* tr4 = reinterpret_cast<const float4*>(trans + i * TAG);
        #pragma unroll
        for (int c = 0; c < 8; ++c) {
            float4 t = tr4[c];
            e[4 * c + 0] = __expf(t.x);
            e[4 * c + 1] = __expf(t.y);
            e[4 * c + 2] = __expf(t.z);
            e[4 * c + 3] = __expf(t.w);
        }
    }

    float v  = (i == START) ? 1.0f : 0.0f;
    float mA = 0.0f;

    // prefetch rings (32-bit, shift-based offsets)
    const float* fp = feats + (unsigned)(b * TAG + i);
    const float* mp = mask + (unsigned)b;          // uniform -> scalar loads
    float fb[PFD], mb[PFD];
    #pragma unroll
    for (int p = 0; p < PFD; ++p) {
        fb[p] = fp[(unsigned)p << 15];
        mb[p] = mp[(unsigned)p << 10];
    }

    for (int t0 = 0; t0 < SEQ; t0 += PFD) {
        // mask monotone in t: if this batch is done, state is frozen forever
        if (mb[0] == 0.0f) break;      // wave-uniform condition

        #pragma unroll
        for (int p = 0; p < PFD; ++p) {
            const int t = t0 + p;

            // gather u via readlane (VALU pipe only — no LDS, no lgkmcnt)
            float s0 = 0.f, s1 = 0.f, s2 = 0.f, s3 = 0.f;
            float s4 = 0.f, s5 = 0.f, s6 = 0.f, s7 = 0.f;
            float v0g = rdlane(v, 0);                // for normalization
            #pragma unroll
            for (int j = 0; j < 4; ++j) {
                s0 = fmaf(rdlane(v, 8 * j + 0), e[8 * j + 0], s0);
                s1 = fmaf(rdlane(v, 8 * j + 1), e[8 * j + 1], s1);
                s2 = fmaf(rdlane(v, 8 * j + 2), e[8 * j + 2], s2);
                s3 = fmaf(rdlane(v, 8 * j + 3), e[8 * j + 3], s3);
                s4 = fmaf(rdlane(v, 8 * j + 4), e[8 * j + 4], s4);
                s5 = fmaf(rdlane(v, 8 * j + 5), e[8 * j + 5], s5);
                s6 = fmaf(rdlane(v, 8 * j + 6), e[8 * j + 6], s6);
                s7 = fmaf(rdlane(v, 8 * j + 7), e[8 * j + 7], s7);
            }
            float dot = ((s0 + s1) + (s2 + s3)) + ((s4 + s5) + (s6 + s7));

            // off-chain: normalizer from committed v[0] (guard first step v0==0)
            bool  ok = (v0g > 0.0f);
            float rr = ok ? __builtin_amdgcn_rcpf(v0g) : 1.0f;
            float lg = ok ? __logf(v0g) : 0.0f;
            float ef = __expf(fb[p]);

            float w   = dot * ef * rr;
            bool  act = (mb[p] != 0.0f);
            v  = act ? w         : v;
            mA = act ? (mA + lg) : mA;

            // ring refill for step t+PFD (clamped; tail re-reads harmless)
            int tn = t + PFD; tn = (tn < SEQ) ? tn : (SEQ - 1);
            fb[p] = fp[(unsigned)tn << 15];
            mb[p] = mp[(unsigned)tn << 10];
        }
    }

    // Epilogue: out[b] = mA + ln( sum_i v_i * exp(trans[END][i]) )
    float z = v * __expf(trans[ENDT * TAG + i]);
    float mx = z;
    #pragma unroll
    for (int k = 16; k >= 1; k >>= 1)
        mx = fmaxf(mx, __shfl_xor(mx, k, 32));
    // guard: z can contain zeros but v[0]>0 ensures mx>0
    float ss = z * __builtin_amdgcn_rcpf(mx);
    #pragma unroll
    for (int k = 16; k >= 1; k >>= 1)
        ss += __shfl_xor(ss, k, 32);
    if (lane == 0) out[b] = mA + __logf(mx) + __logf(ss);
}

extern "C" void kernel_launch(void* const* d_in, const int* in_sizes, int n_in,
                              void* d_out, int out_size, void* d_ws, size_t ws_size,
                              hipStream_t stream) {
    const float* feats = (const float*)d_in[0];
    const float* mask  = (const float*)d_in[1];
    const float* trans = (const float*)d_in[2];
    float* out = (float*)d_out;
    crf_fwd_kernel<<<dim3(BATCH), dim3(64), 0, stream>>>(feats, mask, trans, out);
}